// Round 3
// baseline (12425.220 us; speedup 1.0000x reference)
//
#include <hip/hip_runtime.h>
#include <math.h>

#define IN_DIM 1024
#define MEM 1024
#define NNODE 2048
#define GX_COLS 5120   // [i|o|f|z|u] blocks of 1024

// ---- scan configuration ----
#define NWG 128          // persistent workgroups
#define WGT 768          // 12 waves: 0-7 compute, 8-9 h-poll, 10-11 v-poll(+Gx)
#define DPW 8            // dims per WG  (MEM / NWG)
#define PUBI (NWG * 16)  // ints per parity in a pub buffer (128 WGs x 8 pairs)

__device__ __forceinline__ float fsig(float x) {
  return __builtin_amdgcn_rcpf(1.f + __expf(-x));
}
__device__ __forceinline__ float ftanh(float x) {
  return 1.f - 2.f * __builtin_amdgcn_rcpf(1.f + __expf(2.f * x));
}

// ---- self-validating 8B packets: (float value, int step-tag) ----
__device__ __forceinline__ void store_pair(int* p, float v, int tg) {
  int2 d; d.x = __float_as_int(v); d.y = tg;
  asm volatile("global_store_dwordx2 %0, %1, off sc0 sc1"
               :: "v"(p), "v"(d) : "memory");
}
// poll one producer's 8 pairs (64B) until all tags match, return the values
__device__ __forceinline__ void poll_pairs(const int* p, int tg,
                                           float4& lo, float4& hi) {
  int4 a, b, c, d;
  do {
    asm volatile(
        "global_load_dwordx4 %0, %4, off sc0 sc1\n\t"
        "global_load_dwordx4 %1, %4, off offset:16 sc0 sc1\n\t"
        "global_load_dwordx4 %2, %4, off offset:32 sc0 sc1\n\t"
        "global_load_dwordx4 %3, %4, off offset:48 sc0 sc1\n\t"
        "s_waitcnt vmcnt(0)"
        : "=v"(a), "=v"(b), "=v"(c), "=v"(d)
        : "v"(p) : "memory");
  } while ((a.y ^ tg) | (a.w ^ tg) | (b.y ^ tg) | (b.w ^ tg) |
           (c.y ^ tg) | (c.w ^ tg) | (d.y ^ tg) | (d.w ^ tg));
  lo = make_float4(__int_as_float(a.x), __int_as_float(a.z),
                   __int_as_float(b.x), __int_as_float(b.z));
  hi = make_float4(__int_as_float(c.x), __int_as_float(c.z),
                   __int_as_float(d.x), __int_as_float(d.z));
}

// ---------------- init: seed the pub buffers ----------------
__global__ void init_ctrl(int* h_pub, int* v_pub) {
  int t = threadIdx.x;
  for (int i = t; i < PUBI / 2; i += blockDim.x) {
    h_pub[2 * i + 0] = 0;            // value 0.0f
    h_pub[2 * i + 1] = 0;            // tag 0 (h(0) seed)
  }
  for (int i = t; i < PUBI / 2; i += blockDim.x) {
    h_pub[PUBI + 2 * i + 0] = 0;
    h_pub[PUBI + 2 * i + 1] = -1;    // parity1 invalid
  }
  for (int i = t; i < PUBI; i += blockDim.x) {
    v_pub[2 * i + 0] = 0;
    v_pub[2 * i + 1] = -1;           // both parities invalid
  }
}

// ---------------- Gx = inputs @ Wx + bx ----------------
__global__ __launch_bounds__(256) void gemm_gx(
    const float* __restrict__ A, const float* __restrict__ B,
    const float* __restrict__ bias, float* __restrict__ C) {
  __shared__ float As[8][128];
  __shared__ float Bs[8][132];
  const int tid = threadIdx.x;
  const int bm = blockIdx.y * 128;
  const int bn = blockIdx.x * 128;
  const int tx = tid & 15;
  const int ty = tid >> 4;
  const int am = tid >> 1;
  const int ak = (tid & 1) * 4;
  const int bk = tid >> 5;
  const int bn4 = (tid & 31) * 4;

  float acc[8][8] = {};
  for (int k0 = 0; k0 < IN_DIM; k0 += 8) {
    float4 av = *(const float4*)&A[(size_t)(bm + am) * IN_DIM + k0 + ak];
    float4 bv = *(const float4*)&B[(size_t)(k0 + bk) * GX_COLS + bn + bn4];
    __syncthreads();
    As[ak + 0][am] = av.x;
    As[ak + 1][am] = av.y;
    As[ak + 2][am] = av.z;
    As[ak + 3][am] = av.w;
    *(float4*)&Bs[bk][bn4] = bv;
    __syncthreads();
#pragma unroll
    for (int kk = 0; kk < 8; ++kk) {
      float4 a0 = *(const float4*)&As[kk][ty * 4];
      float4 a1 = *(const float4*)&As[kk][64 + ty * 4];
      float4 b0 = *(const float4*)&Bs[kk][tx * 4];
      float4 b1 = *(const float4*)&Bs[kk][64 + tx * 4];
      float a[8] = {a0.x, a0.y, a0.z, a0.w, a1.x, a1.y, a1.z, a1.w};
      float b[8] = {b0.x, b0.y, b0.z, b0.w, b1.x, b1.y, b1.z, b1.w};
#pragma unroll
      for (int i = 0; i < 8; ++i)
#pragma unroll
        for (int j = 0; j < 8; ++j) acc[i][j] += a[i] * b[j];
    }
  }
  float4 bias0 = *(const float4*)&bias[bn + tx * 4];
  float4 bias1 = *(const float4*)&bias[bn + 64 + tx * 4];
#pragma unroll
  for (int i = 0; i < 8; ++i) {
    int row = bm + ((i < 4) ? (ty * 4 + i) : (64 + ty * 4 + (i - 4)));
    float4 c0 = {acc[i][0] + bias0.x, acc[i][1] + bias0.y,
                 acc[i][2] + bias0.z, acc[i][3] + bias0.w};
    float4 c1 = {acc[i][4] + bias1.x, acc[i][5] + bias1.y,
                 acc[i][6] + bias1.z, acc[i][7] + bias1.w};
    *(float4*)&C[(size_t)row * GX_COLS + bn + tx * 4] = c0;
    *(float4*)&C[(size_t)row * GX_COLS + bn + 64 + tx * 4] = c1;
  }
}

// ---------------- persistent chain scan (wave-specialized) ----------------
// Waves 0-7: compute (wave w owns dim j=wg*8+w; dot layout identical to the
//            proven kernel). Waves 8-9: dedicated h-pollers (always in
//            flight). Waves 10-11: dedicated v-pollers; wave 10 lanes<40
//            also stage Gx. NO in-loop barriers: staging completion is
//            signaled with monotone LDS tags; leaders post (val,tag) 8B LDS
//            pairs; wave 0 lanes 0-7 spin on the 8 tags and issue the same
//            single coalesced 64B publish as before (WRITE_SIZE signature
//            32772 KB must be unchanged).
// Buffer-reuse safety (no barriers needed): any overwrite of h_lds/v_lds/
// gx_lds/share_* at step t+1 is gated by a global publish that transitively
// requires every reader of the step-t contents to have finished (tags are
// monotone; packets self-validating; no ABA).
__global__ __launch_bounds__(WGT) void scan_kernel(
    const float* __restrict__ Wh, const float* __restrict__ bh,
    const float* __restrict__ Wum, const float* __restrict__ bum,
    const float* __restrict__ pic, const float* __restrict__ pfc,
    const float* __restrict__ poc, const float* __restrict__ pzc,
    const float* __restrict__ Gx,
    int* h_pub, int* v_pub,
    float* __restrict__ out) {
  const int wg = blockIdx.x;
  const int tid = threadIdx.x;
  const int w = tid >> 6;    // wave id
  const int ln = tid & 63;
  const int j = wg * DPW + w;          // meaningful for w<8
  const bool leader = (ln == 0);

  __shared__ float h_lds[MEM];
  __shared__ float v_lds[MEM];
  __shared__ float gx_lds[2][5 * DPW];   // [parity][gate*8 + dim]
  __shared__ long long share_v[DPW];     // packed (tag<<32 | val-bits)
  __shared__ long long share_h[DPW];
  __shared__ int h_sig[2];               // monotone: = t+1 when h(t) staged
  __shared__ int v_sig[2];               // monotone: = t+1 when v(t) staged

  // ---- compute-wave register state (dead in poller waves) ----
  float wi[16], wo[16], wf[16], wz[16], wu[16];
  float b_i = 0, b_o = 0, b_f = 0, b_z = 0, b_u = 0;
  float p_i = 0, p_f = 0, p_o = 0, p_z = 0;
  if (w < 8) {
#pragma unroll
    for (int m = 0; m < 4; ++m)
#pragma unroll
      for (int e = 0; e < 4; ++e) {
        int k = ln * 4 + m * 256 + e;
        wi[m * 4 + e] = Wh[(size_t)k * 4096 + 0 * MEM + j];
        wo[m * 4 + e] = Wh[(size_t)k * 4096 + 1 * MEM + j];
        wf[m * 4 + e] = Wh[(size_t)k * 4096 + 2 * MEM + j];
        wz[m * 4 + e] = Wh[(size_t)k * 4096 + 3 * MEM + j];
        wu[m * 4 + e] = Wum[(size_t)k * MEM + j];
      }
    if (leader) {
      b_i = bh[0 * MEM + j]; b_o = bh[1 * MEM + j];
      b_f = bh[2 * MEM + j]; b_z = bh[3 * MEM + j];
      b_u = bum[j];
      p_i = pic[j]; p_f = pfc[j]; p_o = poc[j]; p_z = pzc[j];
    }
  }

  // ---- Gx duty (wave 10, lanes 0..39): prologue stages rows 0 and 1 ----
  const bool gxload = (w == 10) && (ln < 5 * DPW);
  const int g_col = (ln >> 3) * MEM + wg * DPW + (ln & 7);
  float gpre = 0.f;
  if (gxload) {
    gx_lds[0][ln] = Gx[g_col];                       // row 0 -> parity 0
    gx_lds[1][ln] = Gx[(size_t)GX_COLS + g_col];     // row 1 -> parity 1
    gpre = Gx[2 * (size_t)GX_COLS + g_col];          // row 2 prefetched
  }
  if (tid == 0) { h_sig[0] = 0; h_sig[1] = 0; v_sig[0] = 0; v_sig[1] = 0; }
  __syncthreads();   // single prologue barrier; none inside the loop

  if (w < 8) {
    // ================= compute waves =================
    float c = 0.f, hmax = -1e30f;
    float i_keep = 0, f_keep = 0, oh_keep = 0, gux_keep = 0;
    volatile int* hs = h_sig;
    volatile int* vs = v_sig;
    for (int t = 0; t < NNODE; ++t) {
      // ---- wait h(t) staged ----
      while (hs[0] < t + 1 || hs[1] < t + 1) { }
      asm volatile("" ::: "memory");

      float si = 0, so = 0, sf = 0, sz = 0;
#pragma unroll
      for (int m = 0; m < 4; ++m) {
        float4 hv = *(const float4*)&h_lds[m * 256 + ln * 4];
        const float* hh = (const float*)&hv;
#pragma unroll
        for (int e = 0; e < 4; ++e) {
          si += hh[e] * wi[m * 4 + e]; so += hh[e] * wo[m * 4 + e];
          sf += hh[e] * wf[m * 4 + e]; sz += hh[e] * wz[m * 4 + e];
        }
      }
#pragma unroll
      for (int off = 32; off >= 1; off >>= 1) {
        si += __shfl_down(si, off); so += __shfl_down(so, off);
        sf += __shfl_down(sf, off); sz += __shfl_down(sz, off);
      }
      if (leader) {
        const float* gxr = (const float*)gx_lds[t & 1];
        float gix = gxr[w], gox = gxr[8 + w], gfx = gxr[16 + w];
        float gzx = gxr[24 + w], gux = gxr[32 + w];
        float iv = fsig(gix + si + b_i + p_i * c);
        float fv = fsig(gfx + sf + b_f + p_f * c);
        float zv = fsig(gzx + sz + b_z + p_z * c);
        float vv = zv * ftanh(c);
        i_keep = iv; f_keep = fv; oh_keep = gox + so + b_o; gux_keep = gux;
        long long pk = ((long long)(t + 1) << 32) |
                       (unsigned int)__float_as_int(vv);
        ((volatile long long*)share_v)[w] = pk;
      }
      // wave 0 lanes 0-7: gather the 8 tagged pairs, single 64B publish
      if (w == 0 && ln < 8) {
        long long pk;
        do { pk = ((volatile long long*)share_v)[ln]; }
        while ((int)(pk >> 32) != t + 1);
        store_pair(v_pub + (t & 1) * PUBI + wg * 16 + ln * 2,
                   __int_as_float((int)pk), t + 1);
      }

      // ---- wait v(t) staged ----
      while (vs[0] < t + 1 || vs[1] < t + 1) { }
      asm volatile("" ::: "memory");

      float sm = 0;
#pragma unroll
      for (int m = 0; m < 4; ++m) {
        float4 vv4 = *(const float4*)&v_lds[m * 256 + ln * 4];
        const float* vv = (const float*)&vv4;
#pragma unroll
        for (int e = 0; e < 4; ++e) sm += vv[e] * wu[m * 4 + e];
      }
#pragma unroll
      for (int off = 32; off >= 1; off >>= 1) sm += __shfl_down(sm, off);
      if (leader) {
        float uv = ftanh(gux_keep + sm + b_u);
        float cn = i_keep * uv + f_keep * c;
        float ov = fsig(oh_keep + p_o * cn);
        float hn = ov * ftanh(cn);
        c = cn;
        hmax = fmaxf(hmax, hn);
        long long pk = ((long long)(t + 1) << 32) |
                       (unsigned int)__float_as_int(hn);
        ((volatile long long*)share_h)[w] = pk;
      }
      if (w == 0 && ln < 8) {
        long long pk;
        do { pk = ((volatile long long*)share_h)[ln]; }
        while ((int)(pk >> 32) != t + 1);
        store_pair(h_pub + ((t + 1) & 1) * PUBI + wg * 16 + ln * 2,
                   __int_as_float((int)pk), t + 1);
      }
    }
    if (leader) out[j] = hmax;

  } else if (w < 10) {
    // ================= h-poller waves (8,9) =================
    const int idx = tid - 512;   // producer WG 0..127
    for (int t = 0; t < NNODE; ++t) {
      float4 lo, hi;
      poll_pairs(h_pub + (t & 1) * PUBI + idx * 16, t, lo, hi);
      *(float4*)&h_lds[idx * 8] = lo;
      *(float4*)&h_lds[idx * 8 + 4] = hi;
      asm volatile("s_waitcnt lgkmcnt(0)" ::: "memory");
      if (ln == 0) *(volatile int*)&h_sig[w - 8] = t + 1;
    }

  } else {
    // ================= v-poller waves (10,11) + Gx duty =================
    const int idx = tid - 640;   // producer WG 0..127
    for (int t = 0; t < NNODE; ++t) {
      float4 lo, hi;
      poll_pairs(v_pub + (t & 1) * PUBI + idx * 16, t + 1, lo, hi);
      *(float4*)&v_lds[idx * 8] = lo;
      *(float4*)&v_lds[idx * 8 + 4] = hi;
      asm volatile("s_waitcnt lgkmcnt(0)" ::: "memory");
      if (ln == 0) *(volatile int*)&v_sig[w - 10] = t + 1;
      if (gxload) {
        // write row t+2 into parity (t+2)&1 == t&1; consumed-at-t already
        // (v(t) publish depends on the round-A(t) reads of this slot).
        gx_lds[t & 1][ln] = gpre;
        int rn = t + 3; if (rn > NNODE - 1) rn = NNODE - 1;
        gpre = Gx[(size_t)rn * GX_COLS + g_col];
      }
    }
  }
}

extern "C" void kernel_launch(void* const* d_in, const int* in_sizes, int n_in,
                              void* d_out, int out_size, void* d_ws, size_t ws_size,
                              hipStream_t stream) {
  const float* inputs = (const float*)d_in[0];
  const float* Wx  = (const float*)d_in[1];
  const float* bx  = (const float*)d_in[2];
  const float* Wh  = (const float*)d_in[3];
  const float* bh  = (const float*)d_in[4];
  const float* Wum = (const float*)d_in[5];
  const float* bum = (const float*)d_in[6];
  const float* pic = (const float*)d_in[7];
  const float* pfc = (const float*)d_in[8];
  const float* poc = (const float*)d_in[9];
  const float* pzc = (const float*)d_in[10];
  float* out = (float*)d_out;

  // ws: Gx (2048*5120 f32) | h_pub (2*PUBI ints) | v_pub (2*PUBI ints)
  float* Gx = (float*)d_ws;
  int* h_pub = (int*)(Gx + (size_t)NNODE * GX_COLS);
  int* v_pub = h_pub + 2 * PUBI;

  init_ctrl<<<1, 256, 0, stream>>>(h_pub, v_pub);
  gemm_gx<<<dim3(GX_COLS / 128, NNODE / 128), 256, 0, stream>>>(inputs, Wx, bx, Gx);
  scan_kernel<<<NWG, WGT, 0, stream>>>(Wh, bh, Wum, bum, pic, pfc, poc, pzc,
                                       Gx, h_pub, v_pub, out);
}